// Round 3
// baseline (1526.261 us; speedup 1.0000x reference)
//
#include <hip/hip_runtime.h>
#include <stdint.h>

#define NN 10000
#define NE 160000

// ---------- bf16 helpers (raw ushort, OCP bf16 = f32 upper half) ----------
__device__ __forceinline__ float bf2f(unsigned short u) {
    return __uint_as_float(((uint32_t)u) << 16);
}
__device__ __forceinline__ float bflo(uint32_t u) { return __uint_as_float(u << 16); }
__device__ __forceinline__ float bfhi(uint32_t u) { return __uint_as_float(u & 0xffff0000u); }
__device__ __forceinline__ unsigned short f2bf(float f) {
    uint32_t u = __float_as_uint(f);
    u += 0x7fffu + ((u >> 16) & 1u);   // RNE
    return (unsigned short)(u >> 16);
}
__device__ __forceinline__ uint32_t pack2(float lo, float hi) {
    return (uint32_t)f2bf(lo) | ((uint32_t)f2bf(hi) << 16);
}
__device__ __forceinline__ float silu2(float x) {
    return 1.679177f * x / (1.f + __expf(-x));
}
__device__ __forceinline__ int notfinite(float v) {
    return (__float_as_uint(v) & 0x7f800000u) == 0x7f800000u;
}
template<bool BF>
__device__ __forceinline__ float ldin(const void* p, size_t i) {
    if constexpr (BF) return bf2f(((const unsigned short*)p)[i]);
    else              return ((const float*)p)[i];
}

// ---------------------------------------------------------------------------
// K0: dtype detection. bf16 data read as f32 words -> ~8.8% non-finite;
// true f32 N(0,1) data -> 0. Scan 4096 words of node_feats.
// ---------------------------------------------------------------------------
__global__ __launch_bounds__(256) void k_detect(const float* __restrict__ nf,
                                                int* __restrict__ flag) {
    __shared__ int s;
    if (threadIdx.x == 0) s = 0;
    __syncthreads();
    int bad = 0;
    for (int i = threadIdx.x; i < 4096; i += 256) bad |= notfinite(nf[i]);
    if (bad) s = 1;
    __syncthreads();
    if (threadIdx.x == 0) *flag = s;   // 1 = bf16, 0 = f32
}

// ---------------------------------------------------------------------------
// K1: up-projection.  xw[n] layout: [y0 (128) | y1 m-major: 128 + m*128 + v]
// ---------------------------------------------------------------------------
template<bool BF>
__device__ void k_up_body(const void* nfv, const void* Wu0v, const void* Wu1v,
                          float* __restrict__ xw,
                          unsigned short* w0s, unsigned short* w1s) {
    int t = threadIdx.x;
    if constexpr (BF) {
        const uint4* g0 = (const uint4*)Wu0v;
        const uint4* g1 = (const uint4*)Wu1v;
        uint4* s0 = (uint4*)w0s;
        uint4* s1 = (uint4*)w1s;
        for (int i = t; i < 2048; i += 256) { s0[i] = g0[i]; s1[i] = g1[i]; }
    } else {
        const float* g0 = (const float*)Wu0v;
        const float* g1 = (const float*)Wu1v;
        for (int i = t; i < 16384; i += 256) { w0s[i] = f2bf(g0[i]); w1s[i] = f2bf(g1[i]); }
    }
    __syncthreads();
    int j = t & 3, g = t >> 2;           // g in [0,64): wave-uniform type
    bool ty0 = g < 16;
    int m = 0, v0;
    if (ty0) v0 = g << 3;
    else { int gg = g - 16; m = gg >> 4; v0 = (gg & 15) << 3; }
    int n = blockIdx.x * 4 + j;
    const unsigned short* wbase = (ty0 ? w0s : w1s) + v0;
    float acc[8] = {0, 0, 0, 0, 0, 0, 0, 0};
    size_t rowb = (size_t)n * 512;
#pragma unroll 4
    for (int u = 0; u < 128; ++u) {
        uint4 wv = *(const uint4*)(wbase + u * 128);
        int idx = ty0 ? u : (128 + u * 3 + m);
        float xv = ldin<BF>(nfv, rowb + idx);
        acc[0] += xv * bflo(wv.x); acc[1] += xv * bfhi(wv.x);
        acc[2] += xv * bflo(wv.y); acc[3] += xv * bfhi(wv.y);
        acc[4] += xv * bflo(wv.z); acc[5] += xv * bfhi(wv.z);
        acc[6] += xv * bflo(wv.w); acc[7] += xv * bfhi(wv.w);
    }
    int col = ty0 ? v0 : (128 + (m << 7) + v0);
    float* o = xw + (size_t)n * 512 + col;
    const float s = 0.08838834764831845f;   // 1/sqrt(128)
#pragma unroll
    for (int q = 0; q < 8; ++q) o[q] = acc[q] * s;
}
__global__ __launch_bounds__(256) void k_up(const void* nf, const void* Wu0,
                                            const void* Wu1, float* xw,
                                            const int* __restrict__ flag) {
    __shared__ __align__(16) unsigned short w0s[128 * 128];
    __shared__ __align__(16) unsigned short w1s[128 * 128];
    if (*flag) k_up_body<true>(nf, Wu0, Wu1, xw, w0s, w1s);
    else       k_up_body<false>(nf, Wu0, Wu1, xw, w0s, w1s);
}

// ---------------------------------------------------------------------------
// K2: edge MLP stages 1-3 -> h3 (NE x 64, bf16). one edge per thread.
// ---------------------------------------------------------------------------
template<bool BF>
__device__ void k_mlp_a_body(const void* efv, const void* W1v, const void* W2v,
                             const void* W3v, unsigned short* __restrict__ h3w,
                             float* w1t, float* w2t, float* w3t) {
    int t = threadIdx.x;
    for (int i = t; i < 8 * 64; i += 256) {
        int k = i >> 6, jj = i & 63;
        w1t[jj * 8 + k] = ldin<BF>(W1v, i);
    }
    for (int i = t; i < 64 * 64; i += 256) {
        int k = i >> 6, jj = i & 63;
        w2t[jj * 64 + k] = ldin<BF>(W2v, i);
        w3t[jj * 64 + k] = ldin<BF>(W3v, i);
    }
    __syncthreads();
    int e = blockIdx.x * 256 + t;
    float h0[8];
    if constexpr (BF) {
        uint4 ev = *(const uint4*)((const unsigned short*)efv + (size_t)e * 8);
        h0[0] = bflo(ev.x); h0[1] = bfhi(ev.x); h0[2] = bflo(ev.y); h0[3] = bfhi(ev.y);
        h0[4] = bflo(ev.z); h0[5] = bfhi(ev.z); h0[6] = bflo(ev.w); h0[7] = bfhi(ev.w);
    } else {
        const float4* p = (const float4*)((const float*)efv + (size_t)e * 8);
        float4 a = p[0], b = p[1];
        h0[0] = a.x; h0[1] = a.y; h0[2] = a.z; h0[3] = a.w;
        h0[4] = b.x; h0[5] = b.y; h0[6] = b.z; h0[7] = b.w;
    }
    const float sc1 = 0.3535533905932738f;  // 1/sqrt(8)
#pragma unroll
    for (int k = 0; k < 8; ++k) h0[k] *= sc1;

    float ha[64], hb[64];
    for (int jj = 0; jj < 64; ++jj) {
        const float* wr = w1t + jj * 8;
        float s = 0.f;
#pragma unroll
        for (int k = 0; k < 8; ++k) s += h0[k] * wr[k];
        ha[jj] = silu2(s);
    }
    for (int jj = 0; jj < 64; ++jj) {
        const float* wr = w2t + jj * 64;
        float s = 0.f;
#pragma unroll
        for (int k = 0; k < 64; ++k) s += ha[k] * wr[k];
        hb[jj] = silu2(s * 0.125f);
    }
    for (int jj = 0; jj < 64; ++jj) {
        const float* wr = w3t + jj * 64;
        float s = 0.f;
#pragma unroll
        for (int k = 0; k < 64; ++k) s += hb[k] * wr[k];
        ha[jj] = silu2(s * 0.125f);
    }
    uint4* orow = (uint4*)(h3w + (size_t)e * 64);
#pragma unroll
    for (int q = 0; q < 8; ++q) {
        uint4 v;
        v.x = pack2(ha[q * 8 + 0], ha[q * 8 + 1]);
        v.y = pack2(ha[q * 8 + 2], ha[q * 8 + 3]);
        v.z = pack2(ha[q * 8 + 4], ha[q * 8 + 5]);
        v.w = pack2(ha[q * 8 + 6], ha[q * 8 + 7]);
        orow[q] = v;
    }
}
__global__ __launch_bounds__(256) void k_mlp_a(const void* ef, const void* W1,
                                               const void* W2, const void* W3,
                                               unsigned short* h3w,
                                               const int* __restrict__ flag) {
    __shared__ float w1t[64 * 8];
    __shared__ float w2t[64 * 64];
    __shared__ float w3t[64 * 64];
    if (*flag) k_mlp_a_body<true>(ef, W1, W2, W3, h3w, w1t, w2t, w3t);
    else       k_mlp_a_body<false>(ef, W1, W2, W3, h3w, w1t, w2t, w3t);
}

// ---------------------------------------------------------------------------
// K3: CSR build by receiver (zero -> histogram -> scan -> fill)
// ---------------------------------------------------------------------------
__global__ void k_zero(int* __restrict__ p, int n) {
    int i = blockIdx.x * 256 + threadIdx.x;
    if (i < n) p[i] = 0;
}
__global__ void k_hist(const int* __restrict__ ei, int* __restrict__ counts) {
    int e = blockIdx.x * 256 + threadIdx.x;
    if (e < NE) atomicAdd(&counts[ei[NE + e]], 1);
}
__global__ __launch_bounds__(1024) void k_scan(const int* __restrict__ counts,
                                               int* __restrict__ offs,
                                               int* __restrict__ cursor) {
    __shared__ int sums[1024];
    int t = threadIdx.x;
    int base = t * 10;
    int s = 0;
    for (int i = 0; i < 10; ++i) {
        int idx = base + i;
        if (idx < NN) s += counts[idx];
    }
    sums[t] = s;
    __syncthreads();
    for (int d = 1; d < 1024; d <<= 1) {
        int v = (t >= d) ? sums[t - d] : 0;
        __syncthreads();
        if (t >= d) sums[t] += v;
        __syncthreads();
    }
    int run = (t == 0) ? 0 : sums[t - 1];
    for (int i = 0; i < 10; ++i) {
        int idx = base + i;
        if (idx < NN) {
            offs[idx] = run;
            cursor[idx] = run;
            run += counts[idx];
        }
    }
    if (t == 0) offs[NN] = NE;
}
__global__ void k_fill(const int* __restrict__ ei, int* __restrict__ cursor,
                       int* __restrict__ elist) {
    int e = blockIdx.x * 256 + threadIdx.x;
    if (e < NE) {
        int slot = atomicAdd(&cursor[ei[NE + e]], 1);
        elist[slot] = e;
    }
}

// ---------------------------------------------------------------------------
// K4: fused W4-projection + message reduction. block = receiver node.
// Thread t: j = t>>6 (w-block, wave-uniform), cols c0=(t&63)*2, c0+1.
// msg[n] layout (bf16): [m0 (256) | m1 m-major: 256 + m*256 + c]
// ---------------------------------------------------------------------------
template<bool BF>
__device__ void k_msg_body(const float* __restrict__ xw,
                           const unsigned short* __restrict__ h3w,
                           const void* W4v, const void* eav,
                           const int* __restrict__ ei,
                           const int* __restrict__ offs,
                           const int* __restrict__ elist,
                           unsigned short* __restrict__ msgb,
                           unsigned short* w4s) {
    int t = threadIdx.x;
    if constexpr (BF) {
        const uint4* g = (const uint4*)W4v;
        uint4* s = (uint4*)w4s;
        for (int i = t; i < 4096; i += 256) s[i] = g[i];
    } else {
        const float* g = (const float*)W4v;
        for (int i = t; i < 32768; i += 256) w4s[i] = f2bf(g[i]);
    }
    __syncthreads();
    int n = blockIdx.x;
    int j = t >> 6;                 // wave index: 0=w1, 1=w2, 2=w3, 3=w4
    int c0 = (t & 63) * 2;
    int wc = j * 128 + c0;          // ushort col offset into W4 row
    int beg = offs[n], end = offs[n + 1];

    float a0 = 0.f, a1 = 0.f, a2 = 0.f, a3 = 0.f, a4 = 0.f, a5 = 0.f;

    for (int i = beg; i < end; ++i) {
        int e = elist[i];           // block-uniform
        int snd = ei[e];
        float y0, y1x, y1y, y1z;
        if constexpr (BF) {
            uint2 eavv = *(const uint2*)((const unsigned short*)eav + (size_t)e * 4);
            y0 = bflo(eavv.x); y1x = bfhi(eavv.x); y1y = bflo(eavv.y); y1z = bfhi(eavv.y);
        } else {
            float4 eavv = *(const float4*)((const float*)eav + (size_t)e * 4);
            y0 = eavv.x; y1x = eavv.y; y1y = eavv.z; y1z = eavv.w;
        }
        const uint4* hr = (const uint4*)(h3w + (size_t)e * 64);
        uint4 h[8];
#pragma unroll
        for (int q = 0; q < 8; ++q) h[q] = hr[q];

        // d0,d1 = dot(h3row, W4[:, wc], W4[:, wc+1]) / 8
        float d0 = 0.f, d1 = 0.f;
#pragma unroll
        for (int q = 0; q < 8; ++q) {
            uint32_t hv;
            float hk0, hk1;
            uint32_t wv0, wv1;
#define DOT2(HV, KB)                                            \
            hv = (HV);                                          \
            hk0 = bflo(hv); hk1 = bfhi(hv);                     \
            wv0 = *(const uint32_t*)(w4s + (KB) * 512 + wc);    \
            wv1 = *(const uint32_t*)(w4s + ((KB) + 1) * 512 + wc); \
            d0 += hk0 * bflo(wv0); d1 += hk0 * bfhi(wv0);       \
            d0 += hk1 * bflo(wv1); d1 += hk1 * bfhi(wv1);
            DOT2(h[q].x, q * 8 + 0)
            DOT2(h[q].y, q * 8 + 2)
            DOT2(h[q].z, q * 8 + 4)
            DOT2(h[q].w, q * 8 + 6)
#undef DOT2
        }
        d0 *= 0.125f; d1 *= 0.125f;   // /sqrt(64)

        const float* xr = xw + (size_t)snd * 512;
        if (j == 0) {                 // p1[c] = w1*s0*y0 -> m0[c]
            a0 += d0 * xr[c0] * y0;
            a1 += d1 * xr[c0 + 1] * y0;
        } else if (j == 1) {          // p2[c][m] = w2*s0*y1[m] -> m1 rows c
            float ta = d0 * xr[c0], tb = d1 * xr[c0 + 1];
            a0 += ta * y1x; a1 += ta * y1y; a2 += ta * y1z;
            a3 += tb * y1x; a4 += tb * y1y; a5 += tb * y1z;
        } else if (j == 2) {          // p3[c][m] = w3*s1[c][m]*y0 -> m1 rows 128+c
            float f0 = d0 * y0, f1 = d1 * y0;
            a0 += f0 * xr[128 + c0]; a1 += f0 * xr[256 + c0]; a2 += f0 * xr[384 + c0];
            a3 += f1 * xr[128 + c0 + 1]; a4 += f1 * xr[256 + c0 + 1]; a5 += f1 * xr[384 + c0 + 1];
        } else {                      // p4[c] = w4*(s1.y1)/sqrt3 -> m0[128+c]
            float dta = xr[128 + c0] * y1x + xr[256 + c0] * y1y + xr[384 + c0] * y1z;
            float dtb = xr[128 + c0 + 1] * y1x + xr[256 + c0 + 1] * y1y + xr[384 + c0 + 1] * y1z;
            a0 += d0 * dta * 0.5773502691896258f;
            a1 += d1 * dtb * 0.5773502691896258f;
        }
    }

    unsigned short* mr = msgb + (size_t)n * 1024;
    if (j == 0) {
        *(uint32_t*)(mr + c0) = pack2(a0, a1);
    } else if (j == 1) {
        *(uint32_t*)(mr + 256 + c0)       = pack2(a0, a3);
        *(uint32_t*)(mr + 256 + 256 + c0) = pack2(a1, a4);
        *(uint32_t*)(mr + 256 + 512 + c0) = pack2(a2, a5);
    } else if (j == 2) {
        *(uint32_t*)(mr + 256 + 128 + c0)       = pack2(a0, a3);
        *(uint32_t*)(mr + 256 + 256 + 128 + c0) = pack2(a1, a4);
        *(uint32_t*)(mr + 256 + 512 + 128 + c0) = pack2(a2, a5);
    } else {
        *(uint32_t*)(mr + 128 + c0) = pack2(a0, a1);
    }
}
__global__ __launch_bounds__(256) void k_msg(const float* xw, const unsigned short* h3w,
                                             const void* W4, const void* ea,
                                             const int* ei, const int* offs,
                                             const int* elist, unsigned short* msgb,
                                             const int* __restrict__ flag) {
    __shared__ __align__(16) unsigned short w4s[64 * 512];   // 64 KB
    if (*flag) k_msg_body<true>(xw, h3w, W4, ea, ei, offs, elist, msgb, w4s);
    else       k_msg_body<false>(xw, h3w, W4, ea, ei, offs, elist, msgb, w4s);
}

// ---------------------------------------------------------------------------
// K5a: o0 = msg0 @ W_out0 /16/10 -> out cols [0,128)
// K5b: o1[v][m] = sum_u msg1[u][m] W_out1[u][v] /16/10 -> out col 128+v*3+m
// ---------------------------------------------------------------------------
template<bool BF>
__device__ void k_out0_body(const unsigned short* __restrict__ msgb,
                            const void* Wv, void* outv, unsigned short* wls) {
    int t = threadIdx.x;
    if constexpr (BF) {
        const uint4* g = (const uint4*)Wv;
        uint4* s = (uint4*)wls;
        for (int i = t; i < 4096; i += 256) s[i] = g[i];
    } else {
        const float* g = (const float*)Wv;
        for (int i = t; i < 32768; i += 256) wls[i] = f2bf(g[i]);
    }
    __syncthreads();
    int v = t & 127, half = t >> 7;
    for (int jj = 0; jj < 16; ++jj) {
        int n = blockIdx.x * 32 + jj * 2 + half;
        if (n >= NN) break;
        const unsigned short* m0 = msgb + (size_t)n * 1024;
        float acc = 0.f;
#pragma unroll 8
        for (int u = 0; u < 256; ++u) acc += bf2f(m0[u]) * bf2f(wls[u * 128 + v]);
        float r = acc * 0.00625f;
        if constexpr (BF) ((unsigned short*)outv)[(size_t)n * 512 + v] = f2bf(r);
        else              ((float*)outv)[(size_t)n * 512 + v] = r;
    }
}
template<bool BF>
__device__ void k_out1_body(const unsigned short* __restrict__ msgb,
                            const void* Wv, void* outv, unsigned short* wls) {
    int t = threadIdx.x;
    if constexpr (BF) {
        const uint4* g = (const uint4*)Wv;
        uint4* s = (uint4*)wls;
        for (int i = t; i < 4096; i += 256) s[i] = g[i];
    } else {
        const float* g = (const float*)Wv;
        for (int i = t; i < 32768; i += 256) wls[i] = f2bf(g[i]);
    }
    __syncthreads();
    int v = t & 127, half = t >> 7;
    for (int jj = 0; jj < 16; ++jj) {
        int n = blockIdx.x * 32 + jj * 2 + half;
        if (n >= NN) break;
        const unsigned short* m1 = msgb + (size_t)n * 1024 + 256;
        float a0 = 0.f, a1 = 0.f, a2 = 0.f;
#pragma unroll 4
        for (int u = 0; u < 256; ++u) {
            float w = bf2f(wls[u * 128 + v]);
            a0 += bf2f(m1[u]) * w;
            a1 += bf2f(m1[256 + u]) * w;
            a2 += bf2f(m1[512 + u]) * w;
        }
        size_t ob = (size_t)n * 512 + 128 + v * 3;
        if constexpr (BF) {
            unsigned short* o = (unsigned short*)outv;
            o[ob + 0] = f2bf(a0 * 0.00625f);
            o[ob + 1] = f2bf(a1 * 0.00625f);
            o[ob + 2] = f2bf(a2 * 0.00625f);
        } else {
            float* o = (float*)outv;
            o[ob + 0] = a0 * 0.00625f;
            o[ob + 1] = a1 * 0.00625f;
            o[ob + 2] = a2 * 0.00625f;
        }
    }
}
__global__ __launch_bounds__(256) void k_out0(const unsigned short* msgb, const void* W,
                                              void* out, const int* __restrict__ flag) {
    __shared__ __align__(16) unsigned short wls[256 * 128];
    if (*flag) k_out0_body<true>(msgb, W, out, wls);
    else       k_out0_body<false>(msgb, W, out, wls);
}
__global__ __launch_bounds__(256) void k_out1(const unsigned short* msgb, const void* W,
                                              void* out, const int* __restrict__ flag) {
    __shared__ __align__(16) unsigned short wls[256 * 128];
    if (*flag) k_out1_body<true>(msgb, W, out, wls);
    else       k_out1_body<false>(msgb, W, out, wls);
}

// ---------------------------------------------------------------------------
extern "C" void kernel_launch(void* const* d_in, const int* in_sizes, int n_in,
                              void* d_out, int out_size, void* d_ws, size_t ws_size,
                              hipStream_t stream) {
    const void* nf  = d_in[0];
    const void* ea  = d_in[1];
    const void* ef  = d_in[2];
    const int*  ei  = (const int*)d_in[3];
    const void* Wu0 = d_in[4];
    const void* Wu1 = d_in[5];
    const void* W1  = d_in[6];
    const void* W2  = d_in[7];
    const void* W3  = d_in[8];
    const void* W4  = d_in[9];
    const void* Wo0 = d_in[10];
    const void* Wo1 = d_in[11];

    // workspace layout (bytes), total ~62.2 MiB:
    //   [0,          20,480,000)   xw    NN x 512 f32
    //   [20,480,000, 40,960,000)   h3    NE x 64 bf16
    //   [40,960,000, 61,440,000)   msg   NN x 1024 bf16
    //   [61,440,000, ...)          CSR ints + dtype flag
    char* ws = (char*)d_ws;
    float*          xw   = (float*)ws;
    unsigned short* h3w  = (unsigned short*)(ws + 20480000);
    unsigned short* msgb = (unsigned short*)(ws + 40960000);
    int* ib     = (int*)(ws + 61440000);
    int* counts = ib;              // NN
    int* offs   = ib + 10240;      // NN+1
    int* cursor = ib + 20480;      // NN
    int* elist  = ib + 30720;      // NE
    int* flag   = ib + 30720 + NE; // 1

    k_detect<<<1, 256, 0, stream>>>((const float*)nf, flag);
    k_up   <<<2500, 256, 0, stream>>>(nf, Wu0, Wu1, xw, flag);
    k_mlp_a<<<625, 256, 0, stream>>>(ef, W1, W2, W3, h3w, flag);
    k_zero <<<40, 256, 0, stream>>>(counts, NN);
    k_hist <<<625, 256, 0, stream>>>(ei, counts);
    k_scan <<<1, 1024, 0, stream>>>(counts, offs, cursor);
    k_fill <<<625, 256, 0, stream>>>(ei, cursor, elist);
    k_msg  <<<NN, 256, 0, stream>>>(xw, h3w, W4, ea, ei, offs, elist, msgb, flag);
    k_out0 <<<313, 256, 0, stream>>>(msgb, Wo0, d_out, flag);
    k_out1 <<<313, 256, 0, stream>>>(msgb, Wo1, d_out, flag);
}